// Round 7
// baseline (279.810 us; speedup 1.0000x reference)
//
#include <hip/hip_runtime.h>
#include <hip/hip_bf16.h>

#define BATCH 8
#define NN    2048
#define FF    256
#define LL    16
#define GRID  512

typedef float f32x4  __attribute__((ext_vector_type(4)));
typedef float f32x16 __attribute__((ext_vector_type(16)));
typedef short s16x8  __attribute__((ext_vector_type(8)));
typedef unsigned int u32;

static __device__ __forceinline__ unsigned short f2bf(float f) {
    return __builtin_bit_cast(unsigned short, __float2bfloat16(f));
}
static __device__ __forceinline__ float bf2f(unsigned short u) {
    unsigned int x = ((unsigned int)u) << 16;
    return __builtin_bit_cast(float, x);
}

typedef const __attribute__((address_space(1))) unsigned int glb_uint;
typedef __attribute__((address_space(3))) unsigned int lds_uint;
static __device__ __forceinline__ void gload_lds16(const void* g, void* l) {
    __builtin_amdgcn_global_load_lds((glb_uint*)g, (lds_uint*)l, 16, 0, 0);
}

union Smem {
    struct {                                  // phase A  (~41 KB)
        unsigned short xbsh[32 * 268];
        unsigned short Wbsh[16 * 268];
        unsigned short W1bsh[256 * 24];
        unsigned short zbsh[32 * 24];
        float b1sh[256], w2sh[256], pbsh[16];
        float pp[2][32];
    } a;
    struct {                                  // phase Q  (~27 KB)
        unsigned short zsh[2][256 * 24];
        float sqh[2][256];
        float qq[2][32];
    } q;
    struct {                                  // phase M  (~33 KB)
        unsigned short xsh[2][8192];          // 2 x 16KB [f][m], chunk-XOR swz
        float rsp[4][32];
    } m;
};

static __device__ __forceinline__ void gsync(unsigned* cnt) {
    __syncthreads();
    if (threadIdx.x == 0) {
        __threadfence();
        __hip_atomic_fetch_add(cnt, 1u, __ATOMIC_ACQ_REL, __HIP_MEMORY_SCOPE_AGENT);
        while (__hip_atomic_load(cnt, __ATOMIC_ACQUIRE, __HIP_MEMORY_SCOPE_AGENT) < GRID) {
            __builtin_amdgcn_s_sleep(2);
        }
    }
    __syncthreads();
    __threadfence();   // acquire: invalidate L1 before reading other blocks' data
}

// ---------------------------------------------------------------------------
// One kernel, three phases separated by grid syncs.
//   A: z = proj(x) (MFMA), sq, pi = MLP(z) (MFMA), xT transpose      [512 blk]
//   Q: q[n] = sum_m exp(2 z.z - sq_n - sq_m); ce[n] = pi/q * e^-sq   [512 blk]
//   M: out = (1-dt)x + 4dt/row * sum_m w x ; w = exp(2g - sq_n)*ce[m]
//      gram+PV on 32x32x16 MFMA; w stays in registers (shfl_xor pack)
// ---------------------------------------------------------------------------
__global__ __launch_bounds__(256, 2) void tmd_fused(
    const float* __restrict__ x,
    const float* __restrict__ proj_w, const float* __restrict__ proj_b,
    const float* __restrict__ pi_w1,  const float* __restrict__ pi_b1,
    const float* __restrict__ pi_w2,  const float* __restrict__ pi_b2,
    const float* __restrict__ dtp,
    unsigned short* __restrict__ xT,
    unsigned short* __restrict__ zbG,
    float* __restrict__ sqbuf,
    float* __restrict__ pibuf,
    float* __restrict__ cebuf,
    unsigned* __restrict__ syncA,
    unsigned* __restrict__ syncQ,
    float* __restrict__ out)
{
    __shared__ Smem sm;
    const int bid = blockIdx.x;
    const int b = bid & 7;
    const int t = threadIdx.x;
    const int wv = t >> 6, ln = t & 63;
    const int kg = ln >> 4, cl = ln & 15;

    const float* xb = x + (size_t)b * NN * FF;
    unsigned short* xTb = xT + (size_t)b * FF * NN;
    unsigned short* zbW = zbG + (size_t)b * NN * LL;
    const unsigned short* zb = zbG + (size_t)b * NN * LL;
    float* sqW = sqbuf + (size_t)b * NN;
    const float* sqB = sqbuf + (size_t)b * NN;

    // =============================== PHASE A ===============================
    {
        const int nt = bid >> 3;           // 0..63
        const int n0 = nt * 32;
        auto& A = sm.a;

        // stage x tile f32->bf16
#pragma unroll
        for (int i = 0; i < 8; ++i) {
            const int slot = i * 256 + t;
            const int r = slot >> 6, c4 = slot & 63;
            const float4 v = *(const float4*)(xb + (size_t)(n0 + r) * FF + c4 * 4);
            ushort4 o; o.x = f2bf(v.x); o.y = f2bf(v.y); o.z = f2bf(v.z); o.w = f2bf(v.w);
            *(ushort4*)&A.xbsh[r * 268 + c4 * 4] = o;
        }
#pragma unroll
        for (int i = 0; i < 4; ++i) {
            const int slot = i * 256 + t;
            const int l = slot >> 6, c4 = slot & 63;
            const float4 v = *(const float4*)(proj_w + l * FF + c4 * 4);
            ushort4 o; o.x = f2bf(v.x); o.y = f2bf(v.y); o.z = f2bf(v.z); o.w = f2bf(v.w);
            *(ushort4*)&A.Wbsh[l * 268 + c4 * 4] = o;
        }
#pragma unroll
        for (int i = 0; i < 4; ++i) {
            const int slot = i * 256 + t;
            const int f = slot >> 2, q = slot & 3;
            const float4 v = *(const float4*)(pi_w1 + f * LL + q * 4);
            ushort4 o; o.x = f2bf(v.x); o.y = f2bf(v.y); o.z = f2bf(v.z); o.w = f2bf(v.w);
            *(ushort4*)&A.W1bsh[f * 24 + q * 4] = o;
        }
        A.b1sh[t] = pi_b1[t];
        A.w2sh[t] = pi_w2[t];
        if (t < 16) A.pbsh[t] = proj_b[t];
        __syncthreads();

        // proj MFMA (waves 0-1)  ||  xT transpose writes (waves 2-3)
        if (wv < 2) {
            f32x4 zacc = {0.f, 0.f, 0.f, 0.f};
#pragma unroll
            for (int g = 0; g < 8; ++g) {
                const s16x8 af = *(const s16x8*)&A.xbsh[(wv * 16 + cl) * 268 + g * 32 + kg * 8];
                const s16x8 bf = *(const s16x8*)&A.Wbsh[cl * 268 + g * 32 + kg * 8];
                zacc = __builtin_amdgcn_mfma_f32_16x16x32_bf16(af, bf, zacc, 0, 0, 0);
            }
            const float pb = A.pbsh[cl];
#pragma unroll
            for (int r = 0; r < 4; ++r)
                A.zbsh[(wv * 16 + kg * 4 + r) * 24 + cl] = f2bf(zacc[r] + pb);
        } else {
#pragma unroll
            for (int it = 0; it < 16; ++it) {
                const int f = (wv - 2) * 128 + it * 8 + (ln >> 3);
                const int q = ln & 7;
                ushort4 o;
                o.x = A.xbsh[(q * 4 + 0) * 268 + f];
                o.y = A.xbsh[(q * 4 + 1) * 268 + f];
                o.z = A.xbsh[(q * 4 + 2) * 268 + f];
                o.w = A.xbsh[(q * 4 + 3) * 268 + f];
                *(ushort4*)(xTb + (size_t)f * NN + n0 + q * 4) = o;
            }
        }
        __syncthreads();

        // z -> global bf16, sq from bf16 z (exact diagonal)
        if (t < 32) {
            unsigned short zr[16]; float sq = 0.f;
#pragma unroll
            for (int l = 0; l < 16; ++l) {
                zr[l] = A.zbsh[t * 24 + l];
                const float zf = bf2f(zr[l]);
                sq = fmaf(zf, zf, sq);
            }
            unsigned short* dst = zbW + (size_t)(n0 + t) * 16;
            *(uint4*)dst = *(uint4*)&zr[0];
            *(uint4*)(dst + 8) = *(uint4*)&zr[8];
            sqW[n0 + t] = sq;
        }

        // MLP via MFMA: wave -> (ntile = wv&1, f-chunk = wv>>1)
        {
            const int ntl = wv & 1;
            s16x8 bz = {0, 0, 0, 0, 0, 0, 0, 0};
            if (kg < 2) bz = *(const s16x8*)&A.zbsh[(ntl * 16 + cl) * 24 + kg * 8];
            float pisum = 0.f;
            const f32x4 zf4 = {0.f, 0.f, 0.f, 0.f};
#pragma unroll
            for (int j = 0; j < 8; ++j) {
                const int ft = (wv >> 1) * 8 + j;
                s16x8 aw = {0, 0, 0, 0, 0, 0, 0, 0};
                if (kg < 2) aw = *(const s16x8*)&A.W1bsh[(ft * 16 + cl) * 24 + kg * 8];
                const f32x4 h4 = __builtin_amdgcn_mfma_f32_16x16x32_bf16(aw, bz, zf4, 0, 0, 0);
#pragma unroll
                for (int r = 0; r < 4; ++r) {
                    const int f = ft * 16 + kg * 4 + r;
                    const float hh = fmaxf(h4[r] + A.b1sh[f], 0.f);
                    pisum = fmaf(hh, A.w2sh[f], pisum);
                }
            }
            pisum += __shfl_xor(pisum, 16, 64);
            pisum += __shfl_xor(pisum, 32, 64);
            if (ln < 16) A.pp[wv >> 1][ntl * 16 + ln] = pisum;
        }
        __syncthreads();
        if (t < 32) {
            const float tp = A.pp[0][t] + A.pp[1][t] + pi_b2[0];
            pibuf[(size_t)b * NN + n0 + t] = 1.f / (1.f + __expf(-tp));
        }
    }

    gsync(syncA);

    // =============================== PHASE Q ===============================
    {
        const int nt = bid >> 3;
        const int n0 = nt * 32;
        auto& Q = sm.q;

        s16x8 zn = {0, 0, 0, 0, 0, 0, 0, 0};
        if (kg < 2) zn = *(const s16x8*)(zb + (size_t)(n0 + (wv & 1) * 16 + cl) * 16 + kg * 8);
        const float sqn = sqB[n0 + (wv & 1) * 16 + cl];
        const f32x4 zf4 = {0.f, 0.f, 0.f, 0.f};
        float qloc = 0.f;

        uint4 za = *(const uint4*)(zb + (size_t)t * 16);
        uint4 zc = *(const uint4*)(zb + (size_t)t * 16 + 8);
        float sv = sqB[t];
        *(uint4*)&Q.zsh[0][t * 24] = za;
        *(uint4*)&Q.zsh[0][t * 24 + 8] = zc;
        Q.sqh[0][t] = sv;
        __syncthreads();

        const int mbase = (wv >> 1) * 128;
        for (int ch = 0; ch < 8; ++ch) {
            const int cur = ch & 1;
            if (ch < 7) {
                const int m = (ch + 1) * 256 + t;
                za = *(const uint4*)(zb + (size_t)m * 16);
                zc = *(const uint4*)(zb + (size_t)m * 16 + 8);
                sv = sqB[m];
            }
#pragma unroll
            for (int mt = 0; mt < 8; ++mt) {
                s16x8 zm = {0, 0, 0, 0, 0, 0, 0, 0};
                if (kg < 2) zm = *(const s16x8*)&Q.zsh[cur][(mbase + mt * 16 + cl) * 24 + kg * 8];
                const f32x4 g = __builtin_amdgcn_mfma_f32_16x16x32_bf16(zm, zn, zf4, 0, 0, 0);
                const f32x4 sq4 = *(const f32x4*)&Q.sqh[cur][mbase + mt * 16 + kg * 4];
#pragma unroll
                for (int r = 0; r < 4; ++r)
                    qloc += __expf(2.f * g[r] - sq4[r] - sqn);
            }
            if (ch < 7) {
                *(uint4*)&Q.zsh[cur ^ 1][t * 24] = za;
                *(uint4*)&Q.zsh[cur ^ 1][t * 24 + 8] = zc;
                Q.sqh[cur ^ 1][t] = sv;
            }
            __syncthreads();
        }
        qloc += __shfl_xor(qloc, 16, 64);
        qloc += __shfl_xor(qloc, 32, 64);
        if (ln < 16) Q.qq[wv >> 1][(wv & 1) * 16 + ln] = qloc;
        __syncthreads();
        if (t < 32) {
            const size_t gi = (size_t)b * NN + n0 + t;
            // ce = (pi/q) * exp(-sq)  -- folds sqm out of phase-M inner loop
            cebuf[gi] = pibuf[gi] / (Q.qq[0][t] + Q.qq[1][t]) * __expf(-sqB[n0 + t]);
        }
    }

    gsync(syncQ);

    // =============================== PHASE M ===============================
    {
        const int fs = (bid >> 3) & 1;     // f-slab (128)
        const int nt = bid >> 4;           // 0..31, 64n tile
        const int n0 = nt * 64, f0 = fs * 128;
        const int i31 = ln & 31, h = ln >> 5;
        const int nt_w = wv & 1, fs_w = wv >> 1;

        const float* ceB = cebuf + (size_t)b * NN;
        float* ob = out + (size_t)b * NN * FF;
        const float dtv = dtp[0];

        const f32x16 Z16 = {0.f,0.f,0.f,0.f,0.f,0.f,0.f,0.f,
                            0.f,0.f,0.f,0.f,0.f,0.f,0.f,0.f};

        // fixed B operand of the gram: z_n  (col = n = i31, k = l = h*8+j)
        const s16x8 zn = *(const s16x8*)(zb + (size_t)(n0 + nt_w * 32 + i31) * 16 + h * 8);
        const float sqn = sqB[n0 + nt_w * 32 + i31];

        f32x16 acc0 = Z16, acc1 = Z16;
        float rloc = 0.f;

        auto ISSUE = [&](char* dstBase, int kt) {
            const int m0 = kt * 64;
#pragma unroll
            for (int i = 0; i < 4; ++i) {
                const int fl = (i * 4 + wv) * 8 + (ln >> 3);
                const int cp = ln & 7;
                const int clog = cp ^ (fl & 7);
                gload_lds16(xTb + (size_t)(f0 + fl) * NN + m0 + clog * 8,
                            dstBase + (i * 4 + wv) * 1024);
            }
        };
        auto LOADZM = [&](int mG) -> s16x8 {
            return *(const s16x8*)(zb + (size_t)(mG + i31) * 16 + h * 8);
        };

        auto COMPUTE = [&](int kt, const char* xbuf,
                           const s16x8 zc0, const s16x8 zc1,
                           s16x8& zn0, s16x8& zn1, int ktN) {
            s16x8 Afr[2][2];
#pragma unroll
            for (int g = 0; g < 2; ++g) {
                const s16x8 zm = g ? zc1 : zc0;
                const int mG = kt * 64 + g * 32;
                const f32x16 gD = __builtin_amdgcn_mfma_f32_32x32x16_bf16(zm, zn, Z16, 0, 0, 0);
                u32 pk[8];
#pragma unroll
                for (int q = 0; q < 4; ++q) {
                    const f32x4 ce4 = *(const f32x4*)(ceB + mG + 4 * h + 8 * q);
                    const float w0 = __expf(2.f * gD[q * 4 + 0] - sqn) * ce4[0];
                    const float w1 = __expf(2.f * gD[q * 4 + 1] - sqn) * ce4[1];
                    const float w2 = __expf(2.f * gD[q * 4 + 2] - sqn) * ce4[2];
                    const float w3 = __expf(2.f * gD[q * 4 + 3] - sqn) * ce4[3];
                    rloc += (w0 + w1) + (w2 + w3);
                    pk[q * 2 + 0] = (u32)f2bf(w0) | ((u32)f2bf(w1) << 16);
                    pk[q * 2 + 1] = (u32)f2bf(w2) | ((u32)f2bf(w3) << 16);
                }
                u32 sw[8];
#pragma unroll
                for (int p = 0; p < 8; ++p) sw[p] = (u32)__shfl_xor((int)pk[p], 32, 64);
                union { u32 u[4]; s16x8 v; } a0, a1;
                a0.u[0] = h ? sw[2] : pk[0];  a0.u[1] = h ? sw[3] : pk[1];
                a0.u[2] = h ? pk[2] : sw[0];  a0.u[3] = h ? pk[3] : sw[1];
                a1.u[0] = h ? sw[6] : pk[4];  a1.u[1] = h ? sw[7] : pk[5];
                a1.u[2] = h ? pk[6] : sw[4];  a1.u[3] = h ? pk[7] : sw[5];
                Afr[g][0] = a0.v;  Afr[g][1] = a1.v;
            }
            // prefetch next chunk's zm while PV runs
            zn0 = LOADZM(ktN * 64);
            zn1 = LOADZM(ktN * 64 + 32);
            // PV: D[n][f] += w[n][m] * x[m][f]
            const int fl0 = fs_w * 64 + i31;
            const int fl1 = fl0 + 32;
#pragma unroll
            for (int g = 0; g < 2; ++g)
#pragma unroll
                for (int mk = 0; mk < 2; ++mk) {
                    const int c = g * 4 + mk * 2 + h;
                    const s16x8 B0 = *(const s16x8*)(xbuf + fl0 * 128 + (c ^ (fl0 & 7)) * 16);
                    acc0 = __builtin_amdgcn_mfma_f32_32x32x16_bf16(Afr[g][mk], B0, acc0, 0, 0, 0);
                    const s16x8 B1 = *(const s16x8*)(xbuf + fl1 * 128 + (c ^ (fl1 & 7)) * 16);
                    acc1 = __builtin_amdgcn_mfma_f32_32x32x16_bf16(Afr[g][mk], B1, acc1, 0, 0, 0);
                }
        };

        // prologue
        ISSUE((char*)sm.m.xsh[0], 0);
        s16x8 zmA0 = LOADZM(0), zmA1 = LOADZM(32);
        s16x8 zmB0, zmB1;

        for (int kt = 0; kt < 32; kt += 2) {
            __syncthreads();                         // xsh[0] gloads drained
            ISSUE((char*)sm.m.xsh[1], kt + 1);
            COMPUTE(kt, (const char*)sm.m.xsh[0], zmA0, zmA1, zmB0, zmB1, kt + 1);
            __syncthreads();                         // xsh[1] drained
            if (kt + 2 < 32) ISSUE((char*)sm.m.xsh[0], kt + 2);
            COMPUTE(kt + 1, (const char*)sm.m.xsh[1], zmB0, zmB1, zmA0, zmA1,
                    (kt + 2 < 32) ? kt + 2 : 0);
        }

        // rowsum: combine the two k-halves; lane i31 holds rowsum for its n
        rloc += __shfl_xor(rloc, 32, 64);
        if (h == 0) sm.m.rsp[wv][i31] = rloc;

        // epilogue
#pragma unroll
        for (int ft = 0; ft < 2; ++ft) {
            const f32x16 accv = ft ? acc1 : acc0;
            const int fg = f0 + fs_w * 64 + ft * 32 + i31;
#pragma unroll
            for (int r = 0; r < 16; ++r) {
                const int nl = (r & 3) + 8 * (r >> 2) + 4 * h;
                const float rstot = sm.m.rsp[wv][nl] + 1e-5f;
                const float sc = 4.f * dtv / rstot;
                const int ng = n0 + nt_w * 32 + nl;
                const float xv = xb[(size_t)ng * FF + fg];
                ob[(size_t)ng * FF + fg] = (1.f - dtv) * xv + sc * accv[r];
            }
        }
    }
}

// ---------------------------------------------------------------------------
extern "C" void kernel_launch(void* const* d_in, const int* in_sizes, int n_in,
                              void* d_out, int out_size, void* d_ws, size_t ws_size,
                              hipStream_t stream) {
    const float* x      = (const float*)d_in[0];
    const float* proj_w = (const float*)d_in[1];
    const float* proj_b = (const float*)d_in[2];
    const float* pi_w1  = (const float*)d_in[3];
    const float* pi_b1  = (const float*)d_in[4];
    const float* pi_w2  = (const float*)d_in[5];
    const float* pi_b2  = (const float*)d_in[6];
    const float* dtp    = (const float*)d_in[7];
    float* out = (float*)d_out;

    // ws layout: xT 8MB | z bf16 512KB | sq 64KB | pi 64KB | ce 64KB | sync 8B
    unsigned short* xT  = (unsigned short*)d_ws;
    unsigned short* zbG = xT + (size_t)BATCH * FF * NN;
    float* sqbuf = (float*)(zbG + (size_t)BATCH * NN * LL);
    float* pibuf = sqbuf + (size_t)BATCH * NN;
    float* cebuf = pibuf + (size_t)BATCH * NN;
    unsigned* syncp = (unsigned*)(cebuf + (size_t)BATCH * NN);

    hipMemsetAsync(syncp, 0, 2 * sizeof(unsigned), stream);

    tmd_fused<<<dim3(GRID), dim3(256), 0, stream>>>(
        x, proj_w, proj_b, pi_w1, pi_b1, pi_w2, pi_b2, dtp,
        xT, zbG, sqbuf, pibuf, cebuf, syncp, syncp + 1, out);
}